// Round 12
// baseline (98.323 us; speedup 1.0000x reference)
//
#include <hip/hip_runtime.h>
#include <math.h>
#include <string.h>

// GeometricEmbedding: B=4, N=M=3000, d_model=2, sigma_d=1.0
// out[0..12000)  float2 = p0[i] * (sum_m sin d, sum_m cos d)
// out[12000..24000)     = p1[i] * (sum_n sin d, sum_n cos d)
// d = sqrt(max(2 - 2*<p0,p1>, 0))
//
// R18: R17 (2x waves, same time) proved THROUGHPUT-bound. Issue-sum model
// fits R0/R15/R16/R17: time = 24cyc*trans + 2cyc*VALU + 40cyc*gather.
// Trans pipe is the wall; tables lose (gather 40 > sin+cos benefit).
// This round: NO trans ops at all. sqrt -> Quake rsqrt + 2 packed Newton
// (rel 5e-6); sin(d),cos(d) -> degree-8 polys in t=d^2 (cos(sqrt t) and
// sin(sqrt t)/sqrt t are ENTIRE in t; Chebyshev deg-8 on [0,50] ~3e-5 err;
// coefficients fit on HOST in double each launch, passed as kernel args
// duplicated in u64 -> each v_pk_fma's single legal SGPR source).
// All math packed 2 rows/instr via v_pk_{fma,mul,add}_f32 (VOP3P, full
// rate on CDNA). ~168 cyc/step vs 333 -> kernel ~19us, dur ~59-63.

#define GN 3000
#define WMAX 50.0           // poly fit range for t = d^2 (data max ~42)

typedef float f32x2 __attribute__((ext_vector_type(2)));
typedef unsigned long long u64;

// ---- packed f32 asm helpers (d = S0*S1 + S2) ----
__device__ __forceinline__ f32x2 pk_fma_vvv(f32x2 a, f32x2 b, f32x2 c) {
    f32x2 d; asm("v_pk_fma_f32 %0, %1, %2, %3" : "=v"(d) : "v"(a), "v"(b), "v"(c)); return d;
}
__device__ __forceinline__ f32x2 pk_fma_vsv(f32x2 a, u64 b, f32x2 c) {
    f32x2 d; asm("v_pk_fma_f32 %0, %1, %2, %3" : "=v"(d) : "v"(a), "s"(b), "v"(c)); return d;
}
__device__ __forceinline__ f32x2 pk_fma_vvs(f32x2 a, f32x2 b, u64 c) {
    f32x2 d; asm("v_pk_fma_f32 %0, %1, %2, %3" : "=v"(d) : "v"(a), "v"(b), "s"(c)); return d;
}
__device__ __forceinline__ f32x2 pk_mul(f32x2 a, f32x2 b) {
    f32x2 d; asm("v_pk_mul_f32 %0, %1, %2" : "=v"(d) : "v"(a), "v"(b)); return d;
}
__device__ __forceinline__ f32x2 pk_add(f32x2 a, f32x2 b) {
    f32x2 d; asm("v_pk_add_f32 %0, %1, %2" : "=v"(d) : "v"(a), "v"(b)); return d;
}

__device__ __forceinline__ u64 dup2lane0(float lo, float hi) {   // wave-uniform
    unsigned a = (unsigned)__builtin_amdgcn_readfirstlane(__float_as_int(lo));
    unsigned b = (unsigned)__builtin_amdgcn_readfirstlane(__float_as_int(hi));
    return ((u64)b << 32) | (u64)a;
}

struct GeoCoefs {
    u64 p[8];      // sin poly: coef of t^j (j=0..7), fp32 duplicated lo|hi
    u64 q[8];      // cos poly
    u64 onep5;     // 1.5 duplicated (Newton)
    float p8, q8;  // leading t^8 coefficients
};

__global__ __launch_bounds__(256, 4) void geo_emb_kernel(
    const float* __restrict__ p0,
    const float* __restrict__ p1,
    float* __restrict__ out,
    GeoCoefs cf)
{
    const int lane = threadIdx.x & 63;
    const int wid  = (blockIdx.x << 2) | (threadIdx.x >> 6);  // 0..5999 quads

    const bool side0 = (wid < 3000);
    const int quad = side0 ? wid : wid - 3000;
    const int i2   = quad << 2;                 // first row (0..11996), 4 | GN
    const int b    = i2 / GN;                   // magic-mul

    const float2* __restrict__ ownp = (const float2*)(side0 ? p0 : p1);
    const float2* __restrict__ othp = (const float2*)(side0 ? p1 : p0);

    const float2 pr0 = ownp[i2 + 0];
    const float2 pr1 = ownp[i2 + 1];
    const float2 pr2 = ownp[i2 + 2];
    const float2 pr3 = ownp[i2 + 3];

    // t = 2 - 2*dot  (radians^2)
    const u64 axAs = dup2lane0(-2.f * pr0.x, -2.f * pr1.x);
    const u64 ayAs = dup2lane0(-2.f * pr0.y, -2.f * pr1.y);
    const u64 axBs = dup2lane0(-2.f * pr2.x, -2.f * pr3.x);
    const u64 ayBs = dup2lane0(-2.f * pr2.y, -2.f * pr3.y);

    const f32x2 c2v   = {2.0f, 2.0f};
    const f32x2 mhalf = {-0.5f, -0.5f};
    const f32x2 q8v   = {cf.q8, cf.q8};
    const f32x2 p8v   = {cf.p8, cf.p8};

    f32x2 accSA = {0.f, 0.f}, accCA = {0.f, 0.f};
    f32x2 accSB = {0.f, 0.f}, accCB = {0.f, 0.f};

#define EVALPAIR(axs, ays, accS, accC) do {                              \
    f32x2 u_ = pk_fma_vsv(qyy, (ays), c2v);                              \
    f32x2 t_ = pk_fma_vsv(qxx, (axs), u_);                               \
    t_.x = fminf(fmaxf(t_.x, 1e-12f), 50.0f);                            \
    t_.y = fminf(fmaxf(t_.y, 1e-12f), 50.0f);                            \
    f32x2 y_;                                                            \
    y_.x = __int_as_float(0x5f3759df - (__float_as_int(t_.x) >> 1));     \
    y_.y = __int_as_float(0x5f3759df - (__float_as_int(t_.y) >> 1));     \
    f32x2 mht_ = pk_mul(t_, mhalf);                                      \
    f32x2 uu_ = pk_mul(y_, y_);                                          \
    f32x2 w1_ = pk_fma_vvs(mht_, uu_, cf.onep5);                         \
    y_ = pk_mul(y_, w1_);                                                \
    uu_ = pk_mul(y_, y_);                                                \
    w1_ = pk_fma_vvs(mht_, uu_, cf.onep5);                               \
    y_ = pk_mul(y_, w1_);                                                \
    f32x2 d_ = pk_mul(t_, y_);          /* d = t*rsqrt(t) = sqrt(t) */   \
    f32x2 qa_ = pk_fma_vvs(q8v, t_, cf.q[7]);                            \
    qa_ = pk_fma_vvs(qa_, t_, cf.q[6]);                                  \
    qa_ = pk_fma_vvs(qa_, t_, cf.q[5]);                                  \
    qa_ = pk_fma_vvs(qa_, t_, cf.q[4]);                                  \
    qa_ = pk_fma_vvs(qa_, t_, cf.q[3]);                                  \
    qa_ = pk_fma_vvs(qa_, t_, cf.q[2]);                                  \
    qa_ = pk_fma_vvs(qa_, t_, cf.q[1]);                                  \
    qa_ = pk_fma_vvs(qa_, t_, cf.q[0]);                                  \
    f32x2 pa_ = pk_fma_vvs(p8v, t_, cf.p[7]);                            \
    pa_ = pk_fma_vvs(pa_, t_, cf.p[6]);                                  \
    pa_ = pk_fma_vvs(pa_, t_, cf.p[5]);                                  \
    pa_ = pk_fma_vvs(pa_, t_, cf.p[4]);                                  \
    pa_ = pk_fma_vvs(pa_, t_, cf.p[3]);                                  \
    pa_ = pk_fma_vvs(pa_, t_, cf.p[2]);                                  \
    pa_ = pk_fma_vvs(pa_, t_, cf.p[1]);                                  \
    pa_ = pk_fma_vvs(pa_, t_, cf.p[0]);                                  \
    f32x2 sn_ = pk_mul(d_, pa_);        /* sin = d * P(t) */             \
    accS = pk_add(accS, sn_);                                            \
    accC = pk_add(accC, qa_);                                            \
} while (0)

#define STEP(q) do {                                                     \
    f32x2 qxx = { (q).x, (q).x };                                        \
    f32x2 qyy = { (q).y, (q).y };                                        \
    EVALPAIR(axAs, ayAs, accSA, accCA);                                  \
    EVALPAIR(axBs, ayBs, accSB, accCB);                                  \
} while (0)

    const float2* __restrict__ qp = othp + b * GN + lane;
    float2 qA = qp[0];
    #pragma unroll 1
    for (int j = 0; j < 45; ++j) {        // cols lane + {0..44}*64
        float2 qB = qp[64];
        qp += 64;
        STEP(qA);
        qA = qB;
    }
    STEP(qA);                             // col lane + 45*64   (2944 total)
    if (lane < 56) {                      // cols 2944..2999
        float2 qT = qp[64];
        STEP(qT);
    }
#undef STEP
#undef EVALPAIR

    float s0 = accSA.x, c0 = accCA.x, s1 = accSA.y, c1 = accCA.y;
    float s2 = accSB.x, c2 = accCB.x, s3 = accSB.y, c3 = accCB.y;

    #pragma unroll
    for (int off = 32; off >= 1; off >>= 1) {
        s0 += __shfl_down(s0, off, 64);  c0 += __shfl_down(c0, off, 64);
        s1 += __shfl_down(s1, off, 64);  c1 += __shfl_down(c1, off, 64);
        s2 += __shfl_down(s2, off, 64);  c2 += __shfl_down(c2, off, 64);
        s3 += __shfl_down(s3, off, 64);  c3 += __shfl_down(c3, off, 64);
    }

    if (lane == 0) {
        float2* o2 = (float2*)out;
        const int ob = wid << 2;          // side1 quads land at 12000+
        o2[ob + 0] = make_float2(pr0.x * s0, pr0.y * c0);
        o2[ob + 1] = make_float2(pr1.x * s1, pr1.y * c1);
        o2[ob + 2] = make_float2(pr2.x * s2, pr2.y * c2);
        o2[ob + 3] = make_float2(pr3.x * s3, pr3.y * c3);
    }
}

// ---- host: Chebyshev deg-8 fit of f on [0,W], monomial coefficients ----
static void cheb_fit_host(int which /*0=sin(sqrt t)/sqrt t, 1=cos(sqrt t)*/,
                          double W, float* lead, u64* dup /*8: t^0..t^7*/)
{
    const double PI_ = 3.14159265358979323846;
    const int M = 64, DEG = 8;
    double c[DEG + 1];
    for (int j = 0; j <= DEG; ++j) c[j] = 0.0;
    for (int k = 0; k < M; ++k) {
        double th = PI_ * (k + 0.5) / M;
        double u = cos(th);
        double w = 0.5 * W * (u + 1.0);
        double d = sqrt(w);
        double fv = which ? cos(d) : (d < 1e-8 ? 1.0 - w / 6.0 : sin(d) / d);
        for (int j = 0; j <= DEG; ++j) c[j] += fv * cos(j * th);
    }
    for (int j = 0; j <= DEG; ++j) c[j] *= 2.0 / M;
    c[0] *= 0.5;
    // Chebyshev series -> monomial in u
    double mono[DEG + 1], A[DEG + 1], B[DEG + 1], Cc[DEG + 1];
    for (int i = 0; i <= DEG; ++i) { mono[i] = 0; A[i] = 0; B[i] = 0; }
    A[0] = 1.0;  B[1] = 1.0;                     // T0, T1
    mono[0] += c[0];
    mono[1] += c[1];
    for (int j = 2; j <= DEG; ++j) {
        for (int i = 0; i <= DEG; ++i) Cc[i] = -A[i];
        for (int i = 0; i < DEG; ++i)  Cc[i + 1] += 2.0 * B[i];
        for (int i = 0; i <= DEG; ++i) mono[i] += c[j] * Cc[i];
        for (int i = 0; i <= DEG; ++i) { A[i] = B[i]; B[i] = Cc[i]; }
    }
    // substitute u = (2/W)*w - 1  (Horner with polynomial argument)
    double a = 2.0 / W, bb = -1.0, acc[DEG + 1], nxt[DEG + 1];
    for (int i = 0; i <= DEG; ++i) acc[i] = 0;
    acc[0] = mono[DEG];
    for (int j = DEG - 1; j >= 0; --j) {
        for (int i = 0; i <= DEG; ++i) nxt[i] = 0;
        for (int i = 0; i < DEG; ++i) { nxt[i + 1] += acc[i] * a; nxt[i] += acc[i] * bb; }
        nxt[0] += mono[j];
        for (int i = 0; i <= DEG; ++i) acc[i] = nxt[i];
    }
    *lead = (float)acc[DEG];
    for (int j = 0; j < DEG; ++j) {
        float f = (float)acc[j];
        unsigned ui; memcpy(&ui, &f, 4);
        dup[j] = ((u64)ui << 32) | (u64)ui;
    }
}

extern "C" void kernel_launch(void* const* d_in, const int* in_sizes, int n_in,
                              void* d_out, int out_size, void* d_ws, size_t ws_size,
                              hipStream_t stream) {
    const float* points0 = (const float*)d_in[0];
    const float* points1 = (const float*)d_in[1];
    float* out = (float*)d_out;

    GeoCoefs cf;
    cheb_fit_host(0, WMAX, &cf.p8, cf.p);    // sin(sqrt t)/sqrt t
    cheb_fit_host(1, WMAX, &cf.q8, cf.q);    // cos(sqrt t)
    {
        float f = 1.5f; unsigned ui; memcpy(&ui, &f, 4);
        cf.onep5 = ((u64)ui << 32) | (u64)ui;
    }

    dim3 grid(1500);    // 6000 waves x 4 rows = 24000 output rows
    dim3 block(256);
    geo_emb_kernel<<<grid, block, 0, stream>>>(points0, points1, out, cf);
}

// Round 13
// 87.119 us; speedup vs baseline: 1.1286x; 1.1286x over previous
//
#include <hip/hip_runtime.h>
#include <math.h>

// GeometricEmbedding: B=4, N=M=3000, d_model=2, sigma_d=1.0
// out[0..12000)  float2 = p0[i] * (sum_m sin d, sum_m cos d)
// out[12000..24000)     = p1[i] * (sum_n sin d, sum_n cos d)
// d = sqrt(max(2 - 2*<p0,p1>, 0))
//
// R19: R12 finally profiled the main kernel directly: 53us, VALUBusy 70%,
// and solved v_pk_fma_f32 ~ 8cyc/wave64 (FP64 pipe) -> packed f32 is HALF
// scalar rate on gfx950; inline asm also froze scheduling. This round:
// same polynomial idea at fair odds - ALL SCALAR float ops (compiler
// schedules), coefficients host-fit (deg-7 Chebyshev on t=d^2 in [0,50],
// R18's validated fit machinery) passed as plain-float args in SGPRs.
// Per eval: 2 fma (t) + med3 clamp + 1 trans (sqrt - the only irreducible
// one; sin(d)=d*P(t), cos(d)=Q(t) are entire in t) + 14 Horner fma + add
// + fmac = 19 VALU + 1 trans. Per 4-row step: 152 VALU-cyc + 4 trans.
// Model B (pipes overlap cross-wave): ~18us; model A (issue-serialized):
// ~26us. Either beats R0's 37.4; result discriminates A vs B.

#define GN 3000
#define WMAX 50.0           // poly fit range for t = d^2 (data max ~40)

struct GeoCoefs {           // plain floats -> kernel args -> SGPRs
    float q[8];             // cos(sqrt t):      Q(t) = sum q[j] t^j
    float p[8];             // sin(sqrt t)/sqrt: P(t) = sum p[j] t^j
};

__device__ __forceinline__ float sreg(float x) {   // pin wave-uniform to SGPR
    return __int_as_float(__builtin_amdgcn_readfirstlane(__float_as_int(x)));
}

__global__ __launch_bounds__(256, 6) void geo_emb_kernel(
    const float* __restrict__ p0,
    const float* __restrict__ p1,
    float* __restrict__ out,
    GeoCoefs cf)
{
    const int lane = threadIdx.x & 63;
    const int wid  = (blockIdx.x << 2) | (threadIdx.x >> 6);  // 0..5999 quads

    const bool side0 = (wid < 3000);
    const int quad = side0 ? wid : wid - 3000;
    const int i2   = quad << 2;                 // first row (0..11996), 4 | GN
    const int b    = i2 / GN;                   // magic-mul

    const float2* __restrict__ ownp = (const float2*)(side0 ? p0 : p1);
    const float2* __restrict__ othp = (const float2*)(side0 ? p1 : p0);

    const float2 pr0 = ownp[i2 + 0];
    const float2 pr1 = ownp[i2 + 1];
    const float2 pr2 = ownp[i2 + 2];
    const float2 pr3 = ownp[i2 + 3];

    const float ax0 = sreg(-2.f * pr0.x), ay0 = sreg(-2.f * pr0.y);
    const float ax1 = sreg(-2.f * pr1.x), ay1 = sreg(-2.f * pr1.y);
    const float ax2 = sreg(-2.f * pr2.x), ay2 = sreg(-2.f * pr2.y);
    const float ax3 = sreg(-2.f * pr3.x), ay3 = sreg(-2.f * pr3.y);

    float s0 = 0.f, c0 = 0.f, s1 = 0.f, c1 = 0.f;
    float s2 = 0.f, c2 = 0.f, s3 = 0.f, c3 = 0.f;

    // per row: t = 2-2dot (clamped), d = sqrt(t) [trans],
    // cos += Q(t), sin = fma(d, P(t), sin)
#define EVAL(ax, ay, qx, qy, sacc, cacc) do {                            \
    float t_ = fmaf((ax), (qx), fmaf((ay), (qy), 2.0f));                 \
    t_ = fminf(fmaxf(t_, 0.0f), 50.0f);        /* v_med3_f32 */          \
    float d_ = __builtin_amdgcn_sqrtf(t_);                               \
    float qq = fmaf(cf.q[7], t_, cf.q[6]);                               \
    qq = fmaf(qq, t_, cf.q[5]);                                          \
    qq = fmaf(qq, t_, cf.q[4]);                                          \
    qq = fmaf(qq, t_, cf.q[3]);                                          \
    qq = fmaf(qq, t_, cf.q[2]);                                          \
    qq = fmaf(qq, t_, cf.q[1]);                                          \
    qq = fmaf(qq, t_, cf.q[0]);                                          \
    float pp = fmaf(cf.p[7], t_, cf.p[6]);                               \
    pp = fmaf(pp, t_, cf.p[5]);                                          \
    pp = fmaf(pp, t_, cf.p[4]);                                          \
    pp = fmaf(pp, t_, cf.p[3]);                                          \
    pp = fmaf(pp, t_, cf.p[2]);                                          \
    pp = fmaf(pp, t_, cf.p[1]);                                          \
    pp = fmaf(pp, t_, cf.p[0]);                                          \
    (cacc) += qq;                                                        \
    (sacc) = fmaf(d_, pp, (sacc));                                       \
} while (0)

#define STEP(q) do {                                                     \
    EVAL(ax0, ay0, (q).x, (q).y, s0, c0);                                \
    EVAL(ax1, ay1, (q).x, (q).y, s1, c1);                                \
    EVAL(ax2, ay2, (q).x, (q).y, s2, c2);                                \
    EVAL(ax3, ay3, (q).x, (q).y, s3, c3);                                \
} while (0)

    const float2* __restrict__ qp = othp + b * GN + lane;
    float2 qA = qp[0];
    #pragma unroll 1
    for (int j = 0; j < 45; ++j) {        // compute cols lane + {0..44}*64
        float2 qB = qp[64];
        qp += 64;
        STEP(qA);
        qA = qB;
    }
    STEP(qA);                             // col lane + 45*64   (2944 total)
    if (lane < 56) {                      // cols 2944..2999
        float2 qT = qp[64];
        STEP(qT);
    }
#undef STEP
#undef EVAL

    #pragma unroll
    for (int off = 32; off >= 1; off >>= 1) {
        s0 += __shfl_down(s0, off, 64);  c0 += __shfl_down(c0, off, 64);
        s1 += __shfl_down(s1, off, 64);  c1 += __shfl_down(c1, off, 64);
        s2 += __shfl_down(s2, off, 64);  c2 += __shfl_down(c2, off, 64);
        s3 += __shfl_down(s3, off, 64);  c3 += __shfl_down(c3, off, 64);
    }

    if (lane == 0) {
        float2* o2 = (float2*)out;
        const int ob = wid << 2;          // side1 quads land at 12000+
        o2[ob + 0] = make_float2(pr0.x * s0, pr0.y * c0);
        o2[ob + 1] = make_float2(pr1.x * s1, pr1.y * c1);
        o2[ob + 2] = make_float2(pr2.x * s2, pr2.y * c2);
        o2[ob + 3] = make_float2(pr3.x * s3, pr3.y * c3);
    }
}

// ---- host: deg-7 Chebyshev fit of f on [0,W], monomial coefficients ----
// which=0: sin(sqrt t)/sqrt t   which=1: cos(sqrt t)
static void cheb_fit7(int which, double W, float* out8)
{
    const double PI_ = 3.14159265358979323846;
    const int M = 64, DEG = 7;
    double c[DEG + 1];
    for (int j = 0; j <= DEG; ++j) c[j] = 0.0;
    for (int k = 0; k < M; ++k) {
        double th = PI_ * (k + 0.5) / M;
        double u = cos(th);
        double w = 0.5 * W * (u + 1.0);
        double d = sqrt(w);
        double fv = which ? cos(d) : (d < 1e-8 ? 1.0 - w / 6.0 : sin(d) / d);
        for (int j = 0; j <= DEG; ++j) c[j] += fv * cos(j * th);
    }
    for (int j = 0; j <= DEG; ++j) c[j] *= 2.0 / M;
    c[0] *= 0.5;
    // Chebyshev series -> monomial in u
    double mono[DEG + 1], A[DEG + 1], B[DEG + 1], Cc[DEG + 1];
    for (int i = 0; i <= DEG; ++i) { mono[i] = 0; A[i] = 0; B[i] = 0; }
    A[0] = 1.0;  B[1] = 1.0;                     // T0, T1
    mono[0] += c[0];
    mono[1] += c[1];
    for (int j = 2; j <= DEG; ++j) {
        for (int i = 0; i <= DEG; ++i) Cc[i] = -A[i];
        for (int i = 0; i < DEG; ++i)  Cc[i + 1] += 2.0 * B[i];
        for (int i = 0; i <= DEG; ++i) mono[i] += c[j] * Cc[i];
        for (int i = 0; i <= DEG; ++i) { A[i] = B[i]; B[i] = Cc[i]; }
    }
    // substitute u = (2/W)*t - 1  (Horner with polynomial argument)
    double a = 2.0 / W, bb = -1.0, acc[DEG + 1], nxt[DEG + 1];
    for (int i = 0; i <= DEG; ++i) acc[i] = 0;
    acc[0] = mono[DEG];
    for (int j = DEG - 1; j >= 0; --j) {
        for (int i = 0; i <= DEG; ++i) nxt[i] = 0;
        for (int i = 0; i < DEG; ++i) { nxt[i + 1] += acc[i] * a; nxt[i] += acc[i] * bb; }
        nxt[0] += mono[j];
        for (int i = 0; i <= DEG; ++i) acc[i] = nxt[i];
    }
    for (int i = 0; i <= DEG; ++i) out8[i] = (float)acc[i];
}

extern "C" void kernel_launch(void* const* d_in, const int* in_sizes, int n_in,
                              void* d_out, int out_size, void* d_ws, size_t ws_size,
                              hipStream_t stream) {
    const float* points0 = (const float*)d_in[0];
    const float* points1 = (const float*)d_in[1];
    float* out = (float*)d_out;

    GeoCoefs cf;
    cheb_fit7(0, WMAX, cf.p);    // sin(sqrt t)/sqrt t
    cheb_fit7(1, WMAX, cf.q);    // cos(sqrt t)

    dim3 grid(1500);    // 6000 waves x 4 rows = 24000 output rows
    dim3 block(256);
    geo_emb_kernel<<<grid, block, 0, stream>>>(points0, points1, out, cf);
}